// Round 1
// baseline (238.127 us; speedup 1.0000x reference)
//
#include <hip/hip_runtime.h>
#include <cmath>

#define TAPE_SZ 100000
#define N_SZ    50000
#define F_SZ    32
#define B_SZ    128

// ---------------------------------------------------------------------------
// Kernel A: copy tape columns [N_SZ, TAPE_SZ) into out (those survive the set)
// ---------------------------------------------------------------------------
__global__ __launch_bounds__(256) void copy_tail(const float* __restrict__ tape,
                                                 float* __restrict__ out) {
    const int n4 = (TAPE_SZ - N_SZ) / 4;      // 12500 float4 per row
    int i = blockIdx.x * blockDim.x + threadIdx.x;
    int b = blockIdx.y;
    if (i < n4) {
        const float4* src = (const float4*)(tape + (size_t)b * TAPE_SZ + N_SZ);
        float4*       dst = (float4*)(out  + (size_t)b * TAPE_SZ + N_SZ);
        dst[i] = src[i];
    }
}

// ---------------------------------------------------------------------------
// Kernel B: transpose tape (B_SZ x TAPE_SZ) -> tapeT (TAPE_SZ x B_SZ)
// 32x32 LDS tiles; TAPE_SZ % 32 == 0, B_SZ % 32 == 0, no bounds checks.
// ---------------------------------------------------------------------------
__global__ __launch_bounds__(256) void transpose_tape(const float* __restrict__ in,
                                                      float* __restrict__ outT) {
    __shared__ float tile[32][33];
    const int x0 = blockIdx.x * 32;   // tape dim
    const int y0 = blockIdx.y * 32;   // b dim
    #pragma unroll
    for (int k = 0; k < 32; k += 8)
        tile[threadIdx.y + k][threadIdx.x] =
            in[(size_t)(y0 + threadIdx.y + k) * TAPE_SZ + x0 + threadIdx.x];
    __syncthreads();
    #pragma unroll
    for (int k = 0; k < 32; k += 8)
        outT[(size_t)(x0 + threadIdx.y + k) * B_SZ + y0 + threadIdx.x] =
            tile[threadIdx.x][threadIdx.y + k];
}

// ---------------------------------------------------------------------------
// Kernel C: gather-matmul from tapeT, write activated result to out columns.
// Block: dim3(32,8) = 256 threads, handles 32 consecutive n's for all 128 b.
// threadIdx.x indexes b/4 (float4 over b), threadIdx.y*4+i indexes n-local.
// ---------------------------------------------------------------------------
__global__ __launch_bounds__(256) void gather_mm(const float* __restrict__ tapeT,
                                                 const float* __restrict__ weights,
                                                 const float* __restrict__ bias,
                                                 const int*   __restrict__ in_idx,
                                                 const int*   __restrict__ out_idx,
                                                 const int*   __restrict__ act_type,
                                                 float* __restrict__ out) {
    __shared__ int   s_idx[32 * 32];
    __shared__ float s_w[32 * 32];
    __shared__ float s_bias[32];
    __shared__ int   s_act[32];
    __shared__ int   s_oidx[32];
    __shared__ float s_x[32][132];   // [n_local][b], pad to 132 (16B-aligned rows)

    const int tid  = threadIdx.y * 32 + threadIdx.x;
    const int n0   = blockIdx.x * 32;
    const int nmax = (N_SZ - n0 < 32) ? (N_SZ - n0) : 32;

    // Stage indices / weights / per-n metadata in LDS (coalesced).
    for (int t = tid; t < nmax * 32; t += 256) {
        s_idx[t] = in_idx[(size_t)n0 * 32 + t];
        s_w[t]   = weights[(size_t)n0 * 32 + t];
    }
    if (tid < nmax) {
        s_bias[tid] = bias[n0 + tid];
        s_act[tid]  = act_type[n0 + tid];
        s_oidx[tid] = out_idx[n0 + tid];
    }
    __syncthreads();

    const int b4 = threadIdx.x * 4;   // this thread's 4 consecutive b's
    #pragma unroll
    for (int i = 0; i < 4; ++i) {
        const int nl = threadIdx.y * 4 + i;
        if (nl < nmax) {
            float4 acc = make_float4(0.f, 0.f, 0.f, 0.f);
            #pragma unroll 8
            for (int f = 0; f < 32; ++f) {
                const int   idx = s_idx[nl * 32 + f];
                const float w   = s_w[nl * 32 + f];
                const float4 t4 = *(const float4*)(tapeT + (size_t)idx * B_SZ + b4);
                acc.x += t4.x * w;
                acc.y += t4.y * w;
                acc.z += t4.z * w;
                acc.w += t4.w * w;
            }
            const float bz = s_bias[nl];
            acc.x += bz; acc.y += bz; acc.z += bz; acc.w += bz;
            if (s_act[nl] == 0) {
                acc.x = fmaxf(acc.x, 0.f); acc.y = fmaxf(acc.y, 0.f);
                acc.z = fmaxf(acc.z, 0.f); acc.w = fmaxf(acc.w, 0.f);
            } else {
                acc.x = tanhf(acc.x); acc.y = tanhf(acc.y);
                acc.z = tanhf(acc.z); acc.w = tanhf(acc.w);
            }
            *(float4*)(&s_x[nl][b4]) = acc;
        }
    }
    __syncthreads();

    // Write phase: 32 n x 128 b; consecutive tid -> consecutive n (coalesced
    // 128B segments per b-row since output_indices is contiguous).
    const int j     = tid & 31;   // n_local
    const int brow0 = tid >> 5;   // 0..7
    if (j < nmax) {
        const int oc = s_oidx[j];
        #pragma unroll
        for (int k = 0; k < 16; ++k) {
            const int b = brow0 + k * 8;
            out[(size_t)b * TAPE_SZ + oc] = s_x[j][b];
        }
    }
}

// ---------------------------------------------------------------------------
// Fallback (workspace too small): direct uncoalesced gather. Correct, slow.
// ---------------------------------------------------------------------------
__global__ __launch_bounds__(128) void gather_fallback(const float* __restrict__ tape,
                                                       const float* __restrict__ weights,
                                                       const float* __restrict__ bias,
                                                       const int*   __restrict__ in_idx,
                                                       const int*   __restrict__ out_idx,
                                                       const int*   __restrict__ act_type,
                                                       float* __restrict__ out) {
    const int n = blockIdx.x;
    const int b = threadIdx.x;
    float acc = 0.f;
    for (int f = 0; f < F_SZ; ++f) {
        acc += tape[(size_t)b * TAPE_SZ + in_idx[(size_t)n * F_SZ + f]] *
               weights[(size_t)n * F_SZ + f];
    }
    acc += bias[n];
    acc = (act_type[n] == 0) ? fmaxf(acc, 0.f) : tanhf(acc);
    out[(size_t)b * TAPE_SZ + out_idx[n]] = acc;
}

extern "C" void kernel_launch(void* const* d_in, const int* in_sizes, int n_in,
                              void* d_out, int out_size, void* d_ws, size_t ws_size,
                              hipStream_t stream) {
    const float* tape    = (const float*)d_in[0];
    const float* weights = (const float*)d_in[1];
    const float* bias    = (const float*)d_in[2];
    const int*   in_idx  = (const int*)d_in[3];
    const int*   out_idx = (const int*)d_in[4];
    const int*   act     = (const int*)d_in[5];
    float*       out     = (float*)d_out;

    // Columns >= N survive unchanged.
    {
        const int n4 = (TAPE_SZ - N_SZ) / 4;
        dim3 grid((n4 + 255) / 256, B_SZ);
        copy_tail<<<grid, 256, 0, stream>>>(tape, out);
    }

    const size_t need = (size_t)TAPE_SZ * B_SZ * sizeof(float);
    if (ws_size >= need) {
        float* tapeT = (float*)d_ws;
        transpose_tape<<<dim3(TAPE_SZ / 32, B_SZ / 32), dim3(32, 8), 0, stream>>>(tape, tapeT);
        gather_mm<<<dim3((N_SZ + 31) / 32), dim3(32, 8), 0, stream>>>(
            tapeT, weights, bias, in_idx, out_idx, act, out);
    } else {
        gather_fallback<<<dim3(N_SZ), 128, 0, stream>>>(
            tape, weights, bias, in_idx, out_idx, act, out);
    }
}

// Round 2
// 182.488 us; speedup vs baseline: 1.3049x; 1.3049x over previous
//
#include <hip/hip_runtime.h>
#include <hip/hip_bf16.h>
#include <cmath>

#define TAPE_SZ 100000
#define N_SZ    50000
#define F_SZ    32
#define B_SZ    128
#define NB      16      // n's per gather block

// ---------------------------------------------------------------------------
// Kernel A: transpose tape (B x TAPE fp32) -> tapeT (TAPE x B bf16), and
// copy the surviving tail columns [N_SZ, TAPE_SZ) straight to out from the
// same registers (fused copy_tail).
// ---------------------------------------------------------------------------
__global__ __launch_bounds__(256) void transpose_tape(const float* __restrict__ in,
                                                      __hip_bfloat16* __restrict__ outT,
                                                      float* __restrict__ out) {
    __shared__ float tile[32][33];
    const int x0 = blockIdx.x * 32;   // tape dim (TAPE_SZ/32 = 3125 exact)
    const int y0 = blockIdx.y * 32;   // b dim    (B_SZ/32 = 4 exact)
    #pragma unroll
    for (int k = 0; k < 32; k += 8) {
        const int x = x0 + threadIdx.x;
        const int y = y0 + threadIdx.y + k;
        const float v = in[(size_t)y * TAPE_SZ + x];
        tile[threadIdx.y + k][threadIdx.x] = v;
        if (x >= N_SZ) out[(size_t)y * TAPE_SZ + x] = v;   // tail survives
    }
    __syncthreads();
    #pragma unroll
    for (int k = 0; k < 32; k += 8) {
        const int x = x0 + threadIdx.y + k;   // tape pos
        const int b = y0 + threadIdx.x;       // batch
        outT[(size_t)x * B_SZ + b] = __float2bfloat16(tile[threadIdx.x][threadIdx.y + k]);
    }
}

// ---------------------------------------------------------------------------
// Kernel B: gather-matmul from bf16 tapeT.
// Block dim3(16,16)=256: threadIdx.x = b-octet (8 b's via one uint4 load),
// threadIdx.y = n_local (NB=16 n's per block; 50000/16 = 3125 blocks exact).
// ---------------------------------------------------------------------------
__global__ __launch_bounds__(256, 8) void gather_mm(const __hip_bfloat16* __restrict__ tapeT,
                                                    const float* __restrict__ weights,
                                                    const float* __restrict__ bias,
                                                    const int*   __restrict__ in_idx,
                                                    const int*   __restrict__ out_idx,
                                                    const int*   __restrict__ act_type,
                                                    float* __restrict__ out) {
    __shared__ int   s_idx[NB * 32];
    __shared__ float s_w[NB * 32];
    __shared__ float s_bias[NB];
    __shared__ int   s_act[NB];
    __shared__ int   s_oidx[NB];
    __shared__ float s_x[NB][132];   // [n_local][b]; pitch 132: 16B-aligned rows, 2-way-max banks

    const int tid = threadIdx.y * 16 + threadIdx.x;
    const int n0  = blockIdx.x * NB;

    #pragma unroll
    for (int t = tid; t < NB * 32; t += 256) {
        s_idx[t] = in_idx[(size_t)n0 * 32 + t];
        s_w[t]   = weights[(size_t)n0 * 32 + t];
    }
    if (tid < NB) {
        s_bias[tid] = bias[n0 + tid];
        s_act[tid]  = act_type[n0 + tid];
        s_oidx[tid] = out_idx[n0 + tid];
    }
    __syncthreads();

    const int nl = threadIdx.y;
    const int bx = threadIdx.x;           // b = 8*bx .. 8*bx+7
    float a0 = 0.f, a1 = 0.f, a2 = 0.f, a3 = 0.f, a4 = 0.f, a5 = 0.f, a6 = 0.f, a7 = 0.f;

    #pragma unroll 4
    for (int f = 0; f < 32; ++f) {
        const int   idx = s_idx[nl * 32 + f];
        const float w   = s_w[nl * 32 + f];
        const uint4 q   = *(const uint4*)((const unsigned short*)tapeT + (size_t)idx * B_SZ + bx * 8);
        a0 = fmaf(__uint_as_float(q.x << 16),          w, a0);
        a1 = fmaf(__uint_as_float(q.x & 0xffff0000u),  w, a1);
        a2 = fmaf(__uint_as_float(q.y << 16),          w, a2);
        a3 = fmaf(__uint_as_float(q.y & 0xffff0000u),  w, a3);
        a4 = fmaf(__uint_as_float(q.z << 16),          w, a4);
        a5 = fmaf(__uint_as_float(q.z & 0xffff0000u),  w, a5);
        a6 = fmaf(__uint_as_float(q.w << 16),          w, a6);
        a7 = fmaf(__uint_as_float(q.w & 0xffff0000u),  w, a7);
    }

    const float bz = s_bias[nl];
    a0 += bz; a1 += bz; a2 += bz; a3 += bz; a4 += bz; a5 += bz; a6 += bz; a7 += bz;
    if (s_act[nl] == 0) {
        a0 = fmaxf(a0, 0.f); a1 = fmaxf(a1, 0.f); a2 = fmaxf(a2, 0.f); a3 = fmaxf(a3, 0.f);
        a4 = fmaxf(a4, 0.f); a5 = fmaxf(a5, 0.f); a6 = fmaxf(a6, 0.f); a7 = fmaxf(a7, 0.f);
    } else {
        a0 = tanhf(a0); a1 = tanhf(a1); a2 = tanhf(a2); a3 = tanhf(a3);
        a4 = tanhf(a4); a5 = tanhf(a5); a6 = tanhf(a6); a7 = tanhf(a7);
    }
    *(float4*)(&s_x[nl][bx * 8])     = make_float4(a0, a1, a2, a3);
    *(float4*)(&s_x[nl][bx * 8 + 4]) = make_float4(a4, a5, a6, a7);
    __syncthreads();

    // Write: 16 lanes sweep n (consecutive out columns -> 64B segments).
    const int j    = tid & 15;    // n_local
    const int brow = tid >> 4;    // 0..15
    const int oc   = s_oidx[j];
    #pragma unroll
    for (int k = 0; k < 8; ++k) {
        const int b = brow + k * 16;
        out[(size_t)b * TAPE_SZ + oc] = s_x[j][b];
    }
}

// ---------------------------------------------------------------------------
// Fallback (workspace too small): direct uncoalesced gather. Correct, slow.
// ---------------------------------------------------------------------------
__global__ __launch_bounds__(128) void gather_fallback(const float* __restrict__ tape,
                                                       const float* __restrict__ weights,
                                                       const float* __restrict__ bias,
                                                       const int*   __restrict__ in_idx,
                                                       const int*   __restrict__ out_idx,
                                                       const int*   __restrict__ act_type,
                                                       float* __restrict__ out) {
    const int n = blockIdx.x;
    const int b = threadIdx.x;
    float acc = 0.f;
    for (int f = 0; f < F_SZ; ++f) {
        acc += tape[(size_t)b * TAPE_SZ + in_idx[(size_t)n * F_SZ + f]] *
               weights[(size_t)n * F_SZ + f];
    }
    acc += bias[n];
    acc = (act_type[n] == 0) ? fmaxf(acc, 0.f) : tanhf(acc);
    out[(size_t)b * TAPE_SZ + out_idx[n]] = acc;
}

__global__ __launch_bounds__(256) void copy_tail_fb(const float* __restrict__ tape,
                                                    float* __restrict__ out) {
    const int n4 = (TAPE_SZ - N_SZ) / 4;
    int i = blockIdx.x * blockDim.x + threadIdx.x;
    int b = blockIdx.y;
    if (i < n4) {
        const float4* src = (const float4*)(tape + (size_t)b * TAPE_SZ + N_SZ);
        float4*       dst = (float4*)(out  + (size_t)b * TAPE_SZ + N_SZ);
        dst[i] = src[i];
    }
}

extern "C" void kernel_launch(void* const* d_in, const int* in_sizes, int n_in,
                              void* d_out, int out_size, void* d_ws, size_t ws_size,
                              hipStream_t stream) {
    const float* tape    = (const float*)d_in[0];
    const float* weights = (const float*)d_in[1];
    const float* bias    = (const float*)d_in[2];
    const int*   in_idx  = (const int*)d_in[3];
    const int*   out_idx = (const int*)d_in[4];
    const int*   act     = (const int*)d_in[5];
    float*       out     = (float*)d_out;

    const size_t need = (size_t)TAPE_SZ * B_SZ * sizeof(__hip_bfloat16);
    if (ws_size >= need) {
        __hip_bfloat16* tapeT = (__hip_bfloat16*)d_ws;
        transpose_tape<<<dim3(TAPE_SZ / 32, B_SZ / 32), dim3(32, 8), 0, stream>>>(tape, tapeT, out);
        gather_mm<<<dim3(N_SZ / NB), dim3(16, 16), 0, stream>>>(
            tapeT, weights, bias, in_idx, out_idx, act, out);
    } else {
        copy_tail_fb<<<dim3(((TAPE_SZ - N_SZ) / 4 + 255) / 256, B_SZ), 256, 0, stream>>>(tape, out);
        gather_fallback<<<dim3(N_SZ), 128, 0, stream>>>(
            tape, weights, bias, in_idx, out_idx, act, out);
    }
}

// Round 4
// 173.210 us; speedup vs baseline: 1.3748x; 1.0536x over previous
//
#include <hip/hip_runtime.h>
#include <hip/hip_bf16.h>
#include <cmath>

#define TAPE_SZ 100000
#define N_SZ    50000
#define F_SZ    32
#define B_SZ    128
#define NB      16      // n's per gather block

// Manual round-to-nearest-even f32 -> bf16 bits (no __hip_bfloat16 API deps).
static __device__ __forceinline__ unsigned short f32_to_bf16(float f) {
    unsigned int u = __float_as_uint(f);
    u = (u + 0x7fffu + ((u >> 16) & 1u)) >> 16;
    return (unsigned short)u;
}

// ---------------------------------------------------------------------------
// Kernel A: transpose tape (B x TAPE fp32) -> tapeT (TAPE x B bf16) with
// 16B-packed stores, plus fused tail copy (columns >= N_SZ survive into out).
// Block (32,8)=256 threads handles 32 tape-columns x all 128 b.
// Grid: TAPE_SZ/32 = 3125 blocks.
// ---------------------------------------------------------------------------
__global__ __launch_bounds__(256) void transpose_tape(const float* __restrict__ in,
                                                      unsigned short* __restrict__ outT,
                                                      float* __restrict__ out) {
    __shared__ float tile[32][129];   // [x_local][b], pitch 129 -> conflict-free writes
    const int x0 = blockIdx.x * 32;
    const int tx = threadIdx.x;       // x_local 0..31
    const int ty = threadIdx.y;       // 0..7

    const bool tail = (x0 + tx >= N_SZ);
    #pragma unroll
    for (int yy = ty; yy < B_SZ; yy += 8) {
        const float v = in[(size_t)yy * TAPE_SZ + x0 + tx];
        tile[tx][yy] = v;
        if (tail) out[(size_t)yy * TAPE_SZ + x0 + tx] = v;   // surviving tail
    }
    __syncthreads();

    // Write phase: lane -> (x row, b-octet). Consecutive 16 lanes cover one
    // full 256B tapeT row; a wave writes 4 consecutive rows = 1KB contiguous.
    const int tid = ty * 32 + tx;
    const int oct = tid & 15;         // b-octet 0..15 (8 bf16 = 16B each)
    const int xl0 = tid >> 4;         // 0..15
    #pragma unroll
    for (int xx = xl0; xx < 32; xx += 16) {
        const float* src = &tile[xx][oct * 8];
        union { unsigned short u[8]; uint4 q; } pk;
        #pragma unroll
        for (int k = 0; k < 8; ++k)
            pk.u[k] = f32_to_bf16(src[k]);
        *(uint4*)(outT + (size_t)(x0 + xx) * B_SZ + oct * 8) = pk.q;
    }
}

// ---------------------------------------------------------------------------
// Kernel B: gather-matmul from bf16 tapeT.
// Block dim3(16,16)=256: threadIdx.x = b-octet (8 b's via one uint4 load),
// threadIdx.y = n_local (NB=16 n's per block; 50000/16 = 3125 blocks exact).
// ---------------------------------------------------------------------------
__global__ __launch_bounds__(256, 8) void gather_mm(const unsigned short* __restrict__ tapeT,
                                                    const float* __restrict__ weights,
                                                    const float* __restrict__ bias,
                                                    const int*   __restrict__ in_idx,
                                                    const int*   __restrict__ out_idx,
                                                    const int*   __restrict__ act_type,
                                                    float* __restrict__ out) {
    __shared__ int   s_idx[NB * 32];
    __shared__ float s_w[NB * 32];
    __shared__ float s_bias[NB];
    __shared__ int   s_act[NB];
    __shared__ int   s_oidx[NB];
    __shared__ float s_x[NB][132];   // [n_local][b]; pitch 132: 16B-aligned rows

    const int tid = threadIdx.y * 16 + threadIdx.x;
    const int n0  = blockIdx.x * NB;

    #pragma unroll
    for (int t = tid; t < NB * 32; t += 256) {
        s_idx[t] = in_idx[(size_t)n0 * 32 + t];
        s_w[t]   = weights[(size_t)n0 * 32 + t];
    }
    if (tid < NB) {
        s_bias[tid] = bias[n0 + tid];
        s_act[tid]  = act_type[n0 + tid];
        s_oidx[tid] = out_idx[n0 + tid];
    }
    __syncthreads();

    const int nl = threadIdx.y;
    const int bx = threadIdx.x;           // b = 8*bx .. 8*bx+7
    float a0 = 0.f, a1 = 0.f, a2 = 0.f, a3 = 0.f, a4 = 0.f, a5 = 0.f, a6 = 0.f, a7 = 0.f;

    #pragma unroll 8
    for (int f = 0; f < 32; ++f) {
        const int   idx = s_idx[nl * 32 + f];
        const float w   = s_w[nl * 32 + f];
        const uint4 q   = *(const uint4*)(tapeT + (size_t)idx * B_SZ + bx * 8);
        a0 = fmaf(__uint_as_float(q.x << 16),          w, a0);
        a1 = fmaf(__uint_as_float(q.x & 0xffff0000u),  w, a1);
        a2 = fmaf(__uint_as_float(q.y << 16),          w, a2);
        a3 = fmaf(__uint_as_float(q.y & 0xffff0000u),  w, a3);
        a4 = fmaf(__uint_as_float(q.z << 16),          w, a4);
        a5 = fmaf(__uint_as_float(q.z & 0xffff0000u),  w, a5);
        a6 = fmaf(__uint_as_float(q.w << 16),          w, a6);
        a7 = fmaf(__uint_as_float(q.w & 0xffff0000u),  w, a7);
    }

    const float bz = s_bias[nl];
    a0 += bz; a1 += bz; a2 += bz; a3 += bz; a4 += bz; a5 += bz; a6 += bz; a7 += bz;
    if (s_act[nl] == 0) {
        a0 = fmaxf(a0, 0.f); a1 = fmaxf(a1, 0.f); a2 = fmaxf(a2, 0.f); a3 = fmaxf(a3, 0.f);
        a4 = fmaxf(a4, 0.f); a5 = fmaxf(a5, 0.f); a6 = fmaxf(a6, 0.f); a7 = fmaxf(a7, 0.f);
    } else {
        a0 = tanhf(a0); a1 = tanhf(a1); a2 = tanhf(a2); a3 = tanhf(a3);
        a4 = tanhf(a4); a5 = tanhf(a5); a6 = tanhf(a6); a7 = tanhf(a7);
    }
    *(float4*)(&s_x[nl][bx * 8])     = make_float4(a0, a1, a2, a3);
    *(float4*)(&s_x[nl][bx * 8 + 4]) = make_float4(a4, a5, a6, a7);
    __syncthreads();

    // Write: 16 lanes sweep n (consecutive out columns -> 64B segments).
    const int j    = tid & 15;    // n_local
    const int brow = tid >> 4;    // 0..15
    const int oc   = s_oidx[j];
    #pragma unroll
    for (int k = 0; k < 8; ++k) {
        const int b = brow + k * 16;
        out[(size_t)b * TAPE_SZ + oc] = s_x[j][b];
    }
}

// ---------------------------------------------------------------------------
// Fallback (workspace too small): direct uncoalesced gather. Correct, slow.
// ---------------------------------------------------------------------------
__global__ __launch_bounds__(128) void gather_fallback(const float* __restrict__ tape,
                                                       const float* __restrict__ weights,
                                                       const float* __restrict__ bias,
                                                       const int*   __restrict__ in_idx,
                                                       const int*   __restrict__ out_idx,
                                                       const int*   __restrict__ act_type,
                                                       float* __restrict__ out) {
    const int n = blockIdx.x;
    const int b = threadIdx.x;
    float acc = 0.f;
    for (int f = 0; f < F_SZ; ++f) {
        acc += tape[(size_t)b * TAPE_SZ + in_idx[(size_t)n * F_SZ + f]] *
               weights[(size_t)n * F_SZ + f];
    }
    acc += bias[n];
    acc = (act_type[n] == 0) ? fmaxf(acc, 0.f) : tanhf(acc);
    out[(size_t)b * TAPE_SZ + out_idx[n]] = acc;
}

__global__ __launch_bounds__(256) void copy_tail_fb(const float* __restrict__ tape,
                                                    float* __restrict__ out) {
    const int n4 = (TAPE_SZ - N_SZ) / 4;
    int i = blockIdx.x * blockDim.x + threadIdx.x;
    int b = blockIdx.y;
    if (i < n4) {
        const float4* src = (const float4*)(tape + (size_t)b * TAPE_SZ + N_SZ);
        float4*       dst = (float4*)(out  + (size_t)b * TAPE_SZ + N_SZ);
        dst[i] = src[i];
    }
}

extern "C" void kernel_launch(void* const* d_in, const int* in_sizes, int n_in,
                              void* d_out, int out_size, void* d_ws, size_t ws_size,
                              hipStream_t stream) {
    const float* tape    = (const float*)d_in[0];
    const float* weights = (const float*)d_in[1];
    const float* bias    = (const float*)d_in[2];
    const int*   in_idx  = (const int*)d_in[3];
    const int*   out_idx = (const int*)d_in[4];
    const int*   act     = (const int*)d_in[5];
    float*       out     = (float*)d_out;

    const size_t need = (size_t)TAPE_SZ * B_SZ * sizeof(unsigned short);
    if (ws_size >= need) {
        unsigned short* tapeT = (unsigned short*)d_ws;
        transpose_tape<<<dim3(TAPE_SZ / 32), dim3(32, 8), 0, stream>>>(tape, tapeT, out);
        gather_mm<<<dim3(N_SZ / NB), dim3(16, 16), 0, stream>>>(
            tapeT, weights, bias, in_idx, out_idx, act, out);
    } else {
        copy_tail_fb<<<dim3(((TAPE_SZ - N_SZ) / 4 + 255) / 256, B_SZ), 256, 0, stream>>>(tape, out);
        gather_fallback<<<dim3(N_SZ), 128, 0, stream>>>(
            tape, weights, bias, in_idx, out_idx, act, out);
    }
}